// Round 1
// baseline (463.730 us; speedup 1.0000x reference)
//
#include <hip/hip_runtime.h>

// Problem constants (from reference):
//   B=32, T=2048, D=256, P=100000, MAX_SPAN=16
// token_embs: [B,T,D] f32 (64 MiB, fits in 256 MiB L3)
// out: [P, 2D] f32 (204.8 MB)

#define PB_B 32
#define PB_T 2048
#define PB_D 256
#define PB_P 100000

// One wave (64 lanes) per (pair, half) task. Lane l handles the float4 at
// d = 4*l. Span is wave-uniform -> no divergence. Loads are 1 KB contiguous
// per row per wave; stores are 1 KB contiguous per task, 2 KB per pair.
__global__ __launch_bounds__(256) void pair_mean_kernel(
    const float* __restrict__ token_embs,
    const int* __restrict__ p1_start, const int* __restrict__ p1_span,
    const int* __restrict__ p2_start, const int* __restrict__ p2_span,
    const int* __restrict__ pair_batch,
    float* __restrict__ out)
{
    const int wave = threadIdx.x >> 6;   // 0..3
    const int lane = threadIdx.x & 63;   // 0..63
    const long long task = (long long)blockIdx.x * 4 + wave;  // 0 .. 2P-1
    if (task >= 2LL * PB_P) return;

    const int pair = (int)(task >> 1);
    const int half = (int)(task & 1);

    const int b     = pair_batch[pair];
    const int start = half ? p2_start[pair] : p1_start[pair];
    const int span  = half ? p2_span[pair]  : p1_span[pair];

    const float4* __restrict__ src =
        (const float4*)(token_embs + ((long long)b * PB_T + start) * PB_D) + lane;

    float4 acc = make_float4(0.f, 0.f, 0.f, 0.f);
    #pragma unroll 4
    for (int t = 0; t < span; ++t) {
        float4 v = src[(long long)t * (PB_D / 4)];
        acc.x += v.x; acc.y += v.y; acc.z += v.z; acc.w += v.w;
    }
    const float inv = 1.0f / (float)span;
    acc.x *= inv; acc.y *= inv; acc.z *= inv; acc.w *= inv;

    float4* __restrict__ dst =
        (float4*)(out + (long long)pair * (2 * PB_D) + half * PB_D) + lane;
    *dst = acc;
}

extern "C" void kernel_launch(void* const* d_in, const int* in_sizes, int n_in,
                              void* d_out, int out_size, void* d_ws, size_t ws_size,
                              hipStream_t stream) {
    const float* token_embs = (const float*)d_in[0];
    const int* p1_start = (const int*)d_in[1];
    const int* p1_span  = (const int*)d_in[2];
    const int* p2_start = (const int*)d_in[3];
    const int* p2_span  = (const int*)d_in[4];
    const int* pair_batch = (const int*)d_in[5];
    float* out = (float*)d_out;

    // 2P tasks, 4 waves (tasks) per 256-thread block.
    const int n_tasks = 2 * PB_P;
    const int n_blocks = (n_tasks + 3) / 4;  // 50000
    pair_mean_kernel<<<n_blocks, 256, 0, stream>>>(
        token_embs, p1_start, p1_span, p2_start, p2_span, pair_batch, out);
}

// Round 2
// 338.646 us; speedup vs baseline: 1.3694x; 1.3694x over previous
//
#include <hip/hip_runtime.h>

// B=32, T=2048, D=256, P=100000, MAX_SPAN=16
// Strategy: build exclusive prefix-sum csum[B, T+1, D] in d_ws (67 MB),
// then each pair = 4 random 1KB row reads + 2KB write (vs avg 17KB reads direct).

#define PB_B 32
#define PB_T 2048
#define PB_TP1 2049
#define PB_D 256
#define PB_P 100000
#define CHUNK 32                    // rows per chunk
#define NCHUNK (PB_T / CHUNK)       // 64 chunks per batch

// ---------- Pass A: per-chunk sums. One wave per (b, chunk). ----------
__global__ __launch_bounds__(256) void chunk_sum_kernel(
    const float* __restrict__ emb, float* __restrict__ cs)
{
    const int wid  = blockIdx.x * 4 + (threadIdx.x >> 6);   // 0 .. B*NCHUNK-1
    const int lane = threadIdx.x & 63;
    const int b = wid >> 6;
    const int c = wid & (NCHUNK - 1);

    const float4* __restrict__ src =
        (const float4*)(emb + ((long long)b * PB_T + c * CHUNK) * PB_D) + lane;
    float4 acc = make_float4(0.f, 0.f, 0.f, 0.f);
    #pragma unroll
    for (int t = 0; t < CHUNK; ++t) {
        float4 v = src[t * (PB_D / 4)];
        acc.x += v.x; acc.y += v.y; acc.z += v.z; acc.w += v.w;
    }
    ((float4*)(cs + ((long long)b * NCHUNK + c) * PB_D))[lane] = acc;
}

// ---------- Pass B: in-place exclusive scan of chunk sums over c. ----------
__global__ __launch_bounds__(256) void chunk_scan_kernel(float* __restrict__ cs)
{
    const int b = blockIdx.x;       // 32 blocks
    const int d = threadIdx.x;      // 256 threads = one float each, coalesced
    float run = 0.f;
    #pragma unroll
    for (int c = 0; c < NCHUNK; ++c) {
        float* p = cs + ((long long)b * NCHUNK + c) * PB_D + d;
        float v = *p;
        *p = run;
        run += v;
    }
}

// ---------- Pass C: write full csum[B, T+1, D]. One wave per (b, chunk). ----------
__global__ __launch_bounds__(256) void csum_write_kernel(
    const float* __restrict__ emb, const float* __restrict__ cs,
    float* __restrict__ csum)
{
    const int wid  = blockIdx.x * 4 + (threadIdx.x >> 6);
    const int lane = threadIdx.x & 63;
    const int b = wid >> 6;
    const int c = wid & (NCHUNK - 1);

    float4 acc = ((const float4*)(cs + ((long long)b * NCHUNK + c) * PB_D))[lane];
    const float4* __restrict__ src =
        (const float4*)(emb + ((long long)b * PB_T + c * CHUNK) * PB_D) + lane;
    float4* __restrict__ dst =
        (float4*)(csum + ((long long)b * PB_TP1 + c * CHUNK + 1) * PB_D) + lane;

    if (c == 0) {   // zero row csum[b, 0, :]
        ((float4*)(csum + (long long)b * PB_TP1 * PB_D))[lane] =
            make_float4(0.f, 0.f, 0.f, 0.f);
    }
    #pragma unroll
    for (int t = 0; t < CHUNK; ++t) {
        float4 v = src[t * (PB_D / 4)];
        acc.x += v.x; acc.y += v.y; acc.z += v.z; acc.w += v.w;
        dst[t * (PB_D / 4)] = acc;
    }
}

// ---------- Pass D: gather. One wave per pair: 4 row reads, 2KB store. ----------
__global__ __launch_bounds__(256) void gather_kernel(
    const float* __restrict__ csum,
    const int* __restrict__ p1_start, const int* __restrict__ p1_span,
    const int* __restrict__ p2_start, const int* __restrict__ p2_span,
    const int* __restrict__ pair_batch,
    float* __restrict__ out)
{
    const int pair = blockIdx.x * 4 + (threadIdx.x >> 6);
    const int lane = threadIdx.x & 63;
    if (pair >= PB_P) return;

    const int b  = pair_batch[pair];
    const int s1 = p1_start[pair], n1 = p1_span[pair];
    const int s2 = p2_start[pair], n2 = p2_span[pair];

    const float* base = csum + (long long)b * PB_TP1 * PB_D;
    // 4 independent 16B loads per lane (4 coalesced 1KB rows per wave)
    float4 e1 = ((const float4*)(base + (long long)(s1 + n1) * PB_D))[lane];
    float4 b1 = ((const float4*)(base + (long long)s1 * PB_D))[lane];
    float4 e2 = ((const float4*)(base + (long long)(s2 + n2) * PB_D))[lane];
    float4 b2 = ((const float4*)(base + (long long)s2 * PB_D))[lane];

    const float i1 = 1.f / (float)n1;
    const float i2 = 1.f / (float)n2;
    float4 r1 = make_float4((e1.x - b1.x) * i1, (e1.y - b1.y) * i1,
                            (e1.z - b1.z) * i1, (e1.w - b1.w) * i1);
    float4 r2 = make_float4((e2.x - b2.x) * i2, (e2.y - b2.y) * i2,
                            (e2.z - b2.z) * i2, (e2.w - b2.w) * i2);

    float4* o = (float4*)(out + (long long)pair * (2 * PB_D));
    o[lane]      = r1;   // 1KB contiguous
    o[64 + lane] = r2;   // next 1KB
}

// ---------- Fallback (R0 direct kernel) if ws is too small ----------
__global__ __launch_bounds__(256) void pair_mean_direct(
    const float* __restrict__ token_embs,
    const int* __restrict__ p1_start, const int* __restrict__ p1_span,
    const int* __restrict__ p2_start, const int* __restrict__ p2_span,
    const int* __restrict__ pair_batch,
    float* __restrict__ out)
{
    const int wave = threadIdx.x >> 6;
    const int lane = threadIdx.x & 63;
    const long long task = (long long)blockIdx.x * 4 + wave;
    if (task >= 2LL * PB_P) return;
    const int pair = (int)(task >> 1);
    const int half = (int)(task & 1);
    const int b     = pair_batch[pair];
    const int start = half ? p2_start[pair] : p1_start[pair];
    const int span  = half ? p2_span[pair]  : p1_span[pair];
    const float4* src =
        (const float4*)(token_embs + ((long long)b * PB_T + start) * PB_D) + lane;
    float4 acc = make_float4(0.f, 0.f, 0.f, 0.f);
    #pragma unroll 4
    for (int t = 0; t < span; ++t) {
        float4 v = src[(long long)t * (PB_D / 4)];
        acc.x += v.x; acc.y += v.y; acc.z += v.z; acc.w += v.w;
    }
    const float inv = 1.0f / (float)span;
    float4* dst = (float4*)(out + (long long)pair * (2 * PB_D) + half * PB_D) + lane;
    *dst = make_float4(acc.x * inv, acc.y * inv, acc.z * inv, acc.w * inv);
}

extern "C" void kernel_launch(void* const* d_in, const int* in_sizes, int n_in,
                              void* d_out, int out_size, void* d_ws, size_t ws_size,
                              hipStream_t stream) {
    const float* token_embs = (const float*)d_in[0];
    const int* p1_start = (const int*)d_in[1];
    const int* p1_span  = (const int*)d_in[2];
    const int* p2_start = (const int*)d_in[3];
    const int* p2_span  = (const int*)d_in[4];
    const int* pair_batch = (const int*)d_in[5];
    float* out = (float*)d_out;

    const size_t csum_elems = (size_t)PB_B * PB_TP1 * PB_D;            // 67.1 MB
    const size_t cs_elems   = (size_t)PB_B * NCHUNK * PB_D;            // 2 MB
    const size_t need_bytes = (csum_elems + cs_elems) * sizeof(float);

    if (ws_size < need_bytes) {
        // Workspace too small: direct summation path.
        pair_mean_direct<<<(2 * PB_P + 3) / 4, 256, 0, stream>>>(
            token_embs, p1_start, p1_span, p2_start, p2_span, pair_batch, out);
        return;
    }

    float* csum = (float*)d_ws;
    float* cs   = csum + csum_elems;

    const int nwave_bc = PB_B * NCHUNK;               // 2048 waves
    chunk_sum_kernel<<<nwave_bc / 4, 256, 0, stream>>>(token_embs, cs);
    chunk_scan_kernel<<<PB_B, 256, 0, stream>>>(cs);
    csum_write_kernel<<<nwave_bc / 4, 256, 0, stream>>>(token_embs, cs, csum);
    gather_kernel<<<(PB_P + 3) / 4, 256, 0, stream>>>(
        csum, p1_start, p1_span, p2_start, p2_span, pair_batch, out);
}

// Round 3
// 337.635 us; speedup vs baseline: 1.3735x; 1.0030x over previous
//
#include <hip/hip_runtime.h>

// B=32, T=2048, D=256, P=100000, MAX_SPAN=16
// Pipeline:
//   A: chunk sums (CHUNK=64 rows)           cs[B,32,D]
//   B: exclusive scan of cs over chunks
//   C: full exclusive csum[B,T+1,D] (67 MB in ws)
//   H/S/SC: bucket pair indices by batch -> perm[P] (batch-major order)
//   G: gather, XCD-swizzled over batch-major perm so each XCD's L2 holds
//      ~1-2 batch csum slices (2.1 MB each) -> reads mostly L2 hits.

#define PB_B 32
#define PB_T 2048
#define PB_TP1 2049
#define PB_D 256
#define PB_P 100000
#define CHUNK 64
#define NCHUNK (PB_T / CHUNK)   // 32

// ---------- Pass A: per-chunk sums. One wave per (b, chunk). ----------
__global__ __launch_bounds__(256) void chunk_sum_kernel(
    const float* __restrict__ emb, float* __restrict__ cs)
{
    const int wid  = blockIdx.x * 4 + (threadIdx.x >> 6);   // 0 .. B*NCHUNK-1
    const int lane = threadIdx.x & 63;
    const int b = wid >> 5;             // /NCHUNK
    const int c = wid & (NCHUNK - 1);

    const float4* __restrict__ src =
        (const float4*)(emb + ((long long)b * PB_T + c * CHUNK) * PB_D) + lane;
    float4 acc = make_float4(0.f, 0.f, 0.f, 0.f);
    #pragma unroll 8
    for (int t = 0; t < CHUNK; ++t) {
        float4 v = src[t * (PB_D / 4)];
        acc.x += v.x; acc.y += v.y; acc.z += v.z; acc.w += v.w;
    }
    ((float4*)(cs + ((long long)b * NCHUNK + c) * PB_D))[lane] = acc;
}

// ---------- Pass B: in-place exclusive scan of chunk sums over c. ----------
__global__ __launch_bounds__(256) void chunk_scan_kernel(float* __restrict__ cs)
{
    const int b = blockIdx.x;       // 32 blocks
    const int d = threadIdx.x;      // 256 threads, coalesced
    float run = 0.f;
    #pragma unroll
    for (int c = 0; c < NCHUNK; ++c) {
        float* p = cs + ((long long)b * NCHUNK + c) * PB_D + d;
        float v = *p;
        *p = run;
        run += v;
    }
}

// ---------- Pass C: write full exclusive csum[B, T+1, D]. ----------
__global__ __launch_bounds__(256) void csum_write_kernel(
    const float* __restrict__ emb, const float* __restrict__ cs,
    float* __restrict__ csum)
{
    const int wid  = blockIdx.x * 4 + (threadIdx.x >> 6);
    const int lane = threadIdx.x & 63;
    const int b = wid >> 5;
    const int c = wid & (NCHUNK - 1);

    float4 acc = ((const float4*)(cs + ((long long)b * NCHUNK + c) * PB_D))[lane];
    const float4* __restrict__ src =
        (const float4*)(emb + ((long long)b * PB_T + c * CHUNK) * PB_D) + lane;
    float4* __restrict__ dst =
        (float4*)(csum + ((long long)b * PB_TP1 + c * CHUNK + 1) * PB_D) + lane;

    if (c == 0) {
        ((float4*)(csum + (long long)b * PB_TP1 * PB_D))[lane] =
            make_float4(0.f, 0.f, 0.f, 0.f);
    }
    #pragma unroll 8
    for (int t = 0; t < CHUNK; ++t) {
        float4 v = src[t * (PB_D / 4)];
        acc.x += v.x; acc.y += v.y; acc.z += v.z; acc.w += v.w;
        dst[t * (PB_D / 4)] = acc;
    }
}

// ---------- H: per-batch histogram of pairs ----------
__global__ __launch_bounds__(256) void hist_kernel(
    const int* __restrict__ pair_batch, int* __restrict__ counts)
{
    __shared__ int l_cnt[PB_B];
    if (threadIdx.x < PB_B) l_cnt[threadIdx.x] = 0;
    __syncthreads();
    const int i = blockIdx.x * 256 + threadIdx.x;
    if (i < PB_P) atomicAdd(&l_cnt[pair_batch[i]], 1);
    __syncthreads();
    if (threadIdx.x < PB_B && l_cnt[threadIdx.x] > 0)
        atomicAdd(&counts[threadIdx.x], l_cnt[threadIdx.x]);
}

// ---------- S: exclusive scan counts -> cursors (32 bins, 1 thread) ----------
__global__ void scan_counts_kernel(const int* __restrict__ counts,
                                   int* __restrict__ cursors)
{
    if (threadIdx.x == 0 && blockIdx.x == 0) {
        int run = 0;
        #pragma unroll
        for (int b = 0; b < PB_B; ++b) { cursors[b] = run; run += counts[b]; }
    }
}

// ---------- SC: scatter pair indices into batch-major perm ----------
__global__ __launch_bounds__(256) void scatter_kernel(
    const int* __restrict__ pair_batch, int* __restrict__ cursors,
    int* __restrict__ perm)
{
    __shared__ int l_cnt[PB_B];
    __shared__ int l_base[PB_B];
    if (threadIdx.x < PB_B) l_cnt[threadIdx.x] = 0;
    __syncthreads();
    const int i = blockIdx.x * 256 + threadIdx.x;
    int b = 0, lpos = 0;
    const bool valid = (i < PB_P);
    if (valid) { b = pair_batch[i]; lpos = atomicAdd(&l_cnt[b], 1); }
    __syncthreads();
    if (threadIdx.x < PB_B && l_cnt[threadIdx.x] > 0)
        l_base[threadIdx.x] = atomicAdd(&cursors[threadIdx.x], l_cnt[threadIdx.x]);
    __syncthreads();
    if (valid) perm[l_base[b] + lpos] = i;
}

// ---------- G: gather. One wave per pair via batch-major perm, XCD swizzle ----------
__global__ __launch_bounds__(256) void gather_kernel(
    const float* __restrict__ csum, const int* __restrict__ perm,
    const int* __restrict__ p1_start, const int* __restrict__ p1_span,
    const int* __restrict__ p2_start, const int* __restrict__ p2_span,
    const int* __restrict__ pair_batch,
    float* __restrict__ out)
{
    // 25000 blocks; presumed XCD = blockIdx%8. XCD x processes contiguous
    // perm segment [x*3125*4, (x+1)*3125*4) in order -> ~4 batches/XCD.
    const int pos_block = (blockIdx.x & 7) * (25000 / 8) + (blockIdx.x >> 3);
    const int pos = pos_block * 4 + (threadIdx.x >> 6);
    const int lane = threadIdx.x & 63;

    const int pair = perm[pos];
    const int b  = pair_batch[pair];
    const int s1 = p1_start[pair], n1 = p1_span[pair];
    const int s2 = p2_start[pair], n2 = p2_span[pair];

    const float* base = csum + (long long)b * PB_TP1 * PB_D;
    float4 e1 = ((const float4*)(base + (long long)(s1 + n1) * PB_D))[lane];
    float4 b1 = ((const float4*)(base + (long long)s1 * PB_D))[lane];
    float4 e2 = ((const float4*)(base + (long long)(s2 + n2) * PB_D))[lane];
    float4 b2 = ((const float4*)(base + (long long)s2 * PB_D))[lane];

    const float i1 = 1.f / (float)n1;
    const float i2 = 1.f / (float)n2;
    float4 r1 = make_float4((e1.x - b1.x) * i1, (e1.y - b1.y) * i1,
                            (e1.z - b1.z) * i1, (e1.w - b1.w) * i1);
    float4 r2 = make_float4((e2.x - b2.x) * i2, (e2.y - b2.y) * i2,
                            (e2.z - b2.z) * i2, (e2.w - b2.w) * i2);

    float4* o = (float4*)(out + (long long)pair * (2 * PB_D));
    o[lane]      = r1;
    o[64 + lane] = r2;
}

extern "C" void kernel_launch(void* const* d_in, const int* in_sizes, int n_in,
                              void* d_out, int out_size, void* d_ws, size_t ws_size,
                              hipStream_t stream) {
    const float* token_embs = (const float*)d_in[0];
    const int* p1_start = (const int*)d_in[1];
    const int* p1_span  = (const int*)d_in[2];
    const int* p2_start = (const int*)d_in[3];
    const int* p2_span  = (const int*)d_in[4];
    const int* pair_batch = (const int*)d_in[5];
    float* out = (float*)d_out;

    const size_t csum_elems = (size_t)PB_B * PB_TP1 * PB_D;   // 16,785,408
    const size_t cs_elems   = (size_t)PB_B * NCHUNK * PB_D;   // 262,144

    float* csum = (float*)d_ws;
    float* cs   = csum + csum_elems;
    int* counts  = (int*)(cs + cs_elems);
    int* cursors = counts + PB_B;
    int* perm    = cursors + PB_B;

    // csum build
    const int nwave_bc = PB_B * NCHUNK;   // 1024 waves
    chunk_sum_kernel<<<nwave_bc / 4, 256, 0, stream>>>(token_embs, cs);
    chunk_scan_kernel<<<PB_B, 256, 0, stream>>>(cs);
    csum_write_kernel<<<nwave_bc / 4, 256, 0, stream>>>(token_embs, cs, csum);

    // batch bucketing
    hipMemsetAsync(counts, 0, PB_B * sizeof(int), stream);
    const int hb = (PB_P + 255) / 256;    // 391
    hist_kernel<<<hb, 256, 0, stream>>>(pair_batch, counts);
    scan_counts_kernel<<<1, 64, 0, stream>>>(counts, cursors);
    scatter_kernel<<<hb, 256, 0, stream>>>(pair_batch, cursors, perm);

    // gather (P=100000 pairs, 4/block -> 25000 blocks, divisible by 8)
    gather_kernel<<<PB_P / 4, 256, 0, stream>>>(
        csum, perm, p1_start, p1_span, p2_start, p2_span, pair_batch, out);
}